// Round 1
// baseline (350.706 us; speedup 1.0000x reference)
//
#include <hip/hip_runtime.h>
#include <stdint.h>

#define D_MODEL 1024
#define NHEAD   16
#define DHEAD   64
#define BATCH   4
#define SEQ     2048
#define MTOT    (BATCH*SEQ)   // 8192

typedef __attribute__((ext_vector_type(4))) float f32x4;
typedef __attribute__((ext_vector_type(8))) short bf16x8;

typedef __attribute__((address_space(3))) uint32_t lds_u32;
typedef const __attribute__((address_space(1))) uint32_t glb_u32;

__device__ static inline void gload_lds16(const void* g, void* l) {
    __builtin_amdgcn_global_load_lds((glb_u32*)g, (lds_u32*)l, 16, 0, 0);
}

__device__ static inline ushort f2bf(float f) {
    uint32_t u = __builtin_bit_cast(uint32_t, f);
    u += 0x7fffu + ((u >> 16) & 1u);   // RNE (inputs are finite)
    return (ushort)(u >> 16);
}

// ---------------------------------------------------------------- convert
// x [8192,1024] f32 -> bf16 ; Wq,Wk,Wv,Wo [1024,1024] f32 -> bf16 (packed)
__global__ __launch_bounds__(256) void convert_kernel(
    const float4* __restrict__ x,
    const float4* __restrict__ wq, const float4* __restrict__ wk,
    const float4* __restrict__ wv, const float4* __restrict__ wo,
    ushort4* __restrict__ xb, ushort4* __restrict__ wb)
{
    const int NX4 = (MTOT * D_MODEL) / 4;      // 2097152
    const int NW4 = (D_MODEL * D_MODEL) / 4;   // 262144
    const int TOT = NX4 + 4 * NW4;
    for (int i = blockIdx.x * blockDim.x + threadIdx.x; i < TOT;
         i += gridDim.x * blockDim.x) {
        float4 v; ushort4* dst;
        if (i < NX4) { v = x[i]; dst = &xb[i]; }
        else {
            int j = i - NX4;
            int w = j >> 18;            // /262144
            int r = j & (NW4 - 1);
            const float4* s = (w == 0) ? wq : (w == 1) ? wk : (w == 2) ? wv : wo;
            v = s[r]; dst = &wb[(size_t)w * NW4 + r];
        }
        ushort4 o;
        o.x = f2bf(v.x); o.y = f2bf(v.y); o.z = f2bf(v.z); o.w = f2bf(v.w);
        *dst = o;
    }
}

// ---------------------------------------------------------------- GEMM
// C[i,e] = (sum_k A[i,k]*W[e,k] + bias[e]) * scale
// LAYOUT 0: bf16 out at [B,H,S,Dh]   (Q/K)
// LAYOUT 1: bf16 out at [B,H,Dh,S]   (V transposed)
// LAYOUT 2: f32  out row-major [MTOT, D_MODEL]
template<int LAYOUT>
__global__ __launch_bounds__(256) void gemm_bt(
    const ushort* __restrict__ A,   // [8192,1024] bf16
    const ushort* __restrict__ W,   // [1024,1024] bf16
    const float*  __restrict__ bias,
    void* __restrict__ out, float scale)
{
    __shared__ __align__(16) ushort As[128 * 32];
    __shared__ __align__(16) ushort Bs[128 * 32];

    const int tid = threadIdx.x;
    const int w  = tid >> 6, l = tid & 63, lo = l & 15, hi = l >> 4;
    const int wr = w >> 1, wc = w & 1;
    const int m0 = blockIdx.y * 128, n0 = blockIdx.x * 128;

    f32x4 acc[4][4] = {};

    const int srow = l >> 2;          // 0..15
    const int sk   = (l & 3) * 8;     // k element offset

    for (int kt = 0; kt < 32; ++kt) {
        const int k0 = kt * 32;
        __syncthreads();
#pragma unroll
        for (int c = 0; c < 2; ++c) {
            const int row = c * 64 + w * 16 + srow;
            gload_lds16(&A[(size_t)(m0 + row) * 1024 + k0 + sk],
                        &As[(c * 64 + w * 16) * 32]);
            gload_lds16(&W[(size_t)(n0 + row) * 1024 + k0 + sk],
                        &Bs[(c * 64 + w * 16) * 32]);
        }
        __syncthreads();

        bf16x8 af[4], bfr[4];
#pragma unroll
        for (int mi = 0; mi < 4; ++mi)
            af[mi] = *(const bf16x8*)&As[(wr * 64 + mi * 16 + lo) * 32 + hi * 8];
#pragma unroll
        for (int ni = 0; ni < 4; ++ni)
            bfr[ni] = *(const bf16x8*)&Bs[(wc * 64 + ni * 16 + lo) * 32 + hi * 8];
#pragma unroll
        for (int mi = 0; mi < 4; ++mi)
#pragma unroll
            for (int ni = 0; ni < 4; ++ni)
                acc[mi][ni] = __builtin_amdgcn_mfma_f32_16x16x32_bf16(
                    af[mi], bfr[ni], acc[mi][ni], 0, 0, 0);
    }

    // epilogue: C row gi = m0+wr*64+mi*16+hi*4+r ; col gj = n0+wc*64+ni*16+lo
#pragma unroll
    for (int mi = 0; mi < 4; ++mi) {
#pragma unroll
        for (int ni = 0; ni < 4; ++ni) {
            const int gj = n0 + wc * 64 + ni * 16 + lo;
            const float bj = bias[gj];
            if (LAYOUT == 0) {
#pragma unroll
                for (int r = 0; r < 4; ++r) {
                    const int gi = m0 + wr * 64 + mi * 16 + hi * 4 + r;
                    const int b = gi >> 11, s = gi & (SEQ - 1);
                    const int h = gj >> 6, dh = gj & 63;
                    ((ushort*)out)[(((size_t)(b * NHEAD + h)) * SEQ + s) * DHEAD + dh] =
                        f2bf((acc[mi][ni][r] + bj) * scale);
                }
            } else if (LAYOUT == 1) {
                const int gi0 = m0 + wr * 64 + mi * 16 + hi * 4;
                const int b = gi0 >> 11, s = gi0 & (SEQ - 1);
                const int h = gj >> 6, dh = gj & 63;
                ushort4 o4;
                o4.x = f2bf((acc[mi][ni][0] + bj) * scale);
                o4.y = f2bf((acc[mi][ni][1] + bj) * scale);
                o4.z = f2bf((acc[mi][ni][2] + bj) * scale);
                o4.w = f2bf((acc[mi][ni][3] + bj) * scale);
                *(ushort4*)&((ushort*)out)[(((size_t)(b * NHEAD + h)) * DHEAD + dh) * SEQ + s] = o4;
            } else {
#pragma unroll
                for (int r = 0; r < 4; ++r) {
                    const int gi = m0 + wr * 64 + mi * 16 + hi * 4 + r;
                    ((float*)out)[(size_t)gi * D_MODEL + gj] = (acc[mi][ni][r] + bj) * scale;
                }
            }
        }
    }
}

// ---------------------------------------------------------------- attention
// Q [B,H,S,64] (pre-scaled by 1/8), K [B,H,S,64], Vt [B,H,64,S] -> ctx [B,S,1024]
__global__ __launch_bounds__(256) void attn_kernel(
    const ushort* __restrict__ Q, const ushort* __restrict__ K,
    const ushort* __restrict__ Vt, ushort* __restrict__ ctx)
{
    __shared__ __align__(16) ushort Ks[64][72];       // [kv][dh] padded
    __shared__ __align__(16) ushort Vs[64][72];       // [dh][kv] padded
    __shared__ __align__(16) ushort Ps[4][32][72];    // per-wave P [qrow][kv]

    const int tid = threadIdx.x;
    const int w = tid >> 6, l = tid & 63, lo = l & 15, hi = l >> 4;
    const int qt = blockIdx.x, h = blockIdx.y, b = blockIdx.z;
    const int bh = b * NHEAD + h;
    const int q0 = qt * 128;
    const size_t base = (size_t)bh * SEQ * DHEAD;   // same for Q,K,Vt

    // Q fragments in registers (rows q0+w*32+mi*16+lo, k = ks*32+hi*8)
    bf16x8 qf[2][2];
#pragma unroll
    for (int mi = 0; mi < 2; ++mi)
#pragma unroll
        for (int ks = 0; ks < 2; ++ks)
            qf[mi][ks] = *(const bf16x8*)&Q[base +
                (size_t)(q0 + w * 32 + mi * 16 + lo) * DHEAD + ks * 32 + hi * 8];

    f32x4 o[2][4] = {};
    float mrow[2][4], lrow[2][4];
#pragma unroll
    for (int mi = 0; mi < 2; ++mi)
#pragma unroll
        for (int r = 0; r < 4; ++r) { mrow[mi][r] = -1e30f; lrow[mi][r] = 0.f; }

    const int ntiles = (q0 + 128) / 64;
    const int krow = tid >> 3;            // 0..31
    const int kcol = (tid & 7) * 8;

    for (int t = 0; t < ntiles; ++t) {
        const int kv0 = t * 64;
        bf16x8 kreg[2], vreg[2];
#pragma unroll
        for (int c = 0; c < 2; ++c) {
            kreg[c] = *(const bf16x8*)&K[base + (size_t)(kv0 + c * 32 + krow) * DHEAD + kcol];
            vreg[c] = *(const bf16x8*)&Vt[base + (size_t)(c * 32 + krow) * SEQ + kv0 + kcol];
        }
        __syncthreads();   // all waves done reading previous K/V tiles
#pragma unroll
        for (int c = 0; c < 2; ++c) {
            *(bf16x8*)&Ks[c * 32 + krow][kcol] = kreg[c];
            *(bf16x8*)&Vs[c * 32 + krow][kcol] = vreg[c];
        }
        __syncthreads();

        // ---- S = Q K^T  (Q pre-scaled)
        f32x4 s[2][4] = {};
#pragma unroll
        for (int ks = 0; ks < 2; ++ks) {
            bf16x8 kf[4];
#pragma unroll
            for (int ni = 0; ni < 4; ++ni)
                kf[ni] = *(const bf16x8*)&Ks[ni * 16 + lo][ks * 32 + hi * 8];
#pragma unroll
            for (int mi = 0; mi < 2; ++mi)
#pragma unroll
                for (int ni = 0; ni < 4; ++ni)
                    s[mi][ni] = __builtin_amdgcn_mfma_f32_16x16x32_bf16(
                        qf[mi][ks], kf[ni], s[mi][ni], 0, 0, 0);
        }

        // ---- causal mask (wave-uniform skip when tile fully unmasked)
        if (kv0 + 63 > q0 + w * 32) {
#pragma unroll
            for (int mi = 0; mi < 2; ++mi)
#pragma unroll
                for (int r = 0; r < 4; ++r) {
                    const int gq = q0 + w * 32 + mi * 16 + hi * 4 + r;
#pragma unroll
                    for (int ni = 0; ni < 4; ++ni) {
                        const int gk = kv0 + ni * 16 + lo;
                        if (gk > gq) s[mi][ni][r] = -1e30f;
                    }
                }
        }

        // ---- online softmax (row r lives across 16 'lo' lanes)
#pragma unroll
        for (int mi = 0; mi < 2; ++mi)
#pragma unroll
            for (int r = 0; r < 4; ++r) {
                float tmax = fmaxf(fmaxf(s[mi][0][r], s[mi][1][r]),
                                   fmaxf(s[mi][2][r], s[mi][3][r]));
                tmax = fmaxf(tmax, __shfl_xor(tmax, 1));
                tmax = fmaxf(tmax, __shfl_xor(tmax, 2));
                tmax = fmaxf(tmax, __shfl_xor(tmax, 4));
                tmax = fmaxf(tmax, __shfl_xor(tmax, 8));
                const float mnew = fmaxf(mrow[mi][r], tmax);
                const float corr = __expf(mrow[mi][r] - mnew);
                mrow[mi][r] = mnew;
                float lsum = 0.f;
#pragma unroll
                for (int ni = 0; ni < 4; ++ni) {
                    const float p = __expf(s[mi][ni][r] - mnew);
                    s[mi][ni][r] = p;
                    lsum += p;
                }
                lsum += __shfl_xor(lsum, 1);
                lsum += __shfl_xor(lsum, 2);
                lsum += __shfl_xor(lsum, 4);
                lsum += __shfl_xor(lsum, 8);
                lrow[mi][r] = lrow[mi][r] * corr + lsum;
#pragma unroll
                for (int ni = 0; ni < 4; ++ni)
                    o[mi][ni][r] *= corr;
            }

        // ---- P -> LDS (wave-private, bf16)
#pragma unroll
        for (int mi = 0; mi < 2; ++mi)
#pragma unroll
            for (int ni = 0; ni < 4; ++ni)
#pragma unroll
                for (int r = 0; r < 4; ++r)
                    Ps[w][mi * 16 + hi * 4 + r][ni * 16 + lo] = f2bf(s[mi][ni][r]);

        // ---- O += P V
#pragma unroll
        for (int ks2 = 0; ks2 < 2; ++ks2) {
            bf16x8 pf[2], vf[4];
#pragma unroll
            for (int mi = 0; mi < 2; ++mi)
                pf[mi] = *(const bf16x8*)&Ps[w][mi * 16 + lo][ks2 * 32 + hi * 8];
#pragma unroll
            for (int ni = 0; ni < 4; ++ni)
                vf[ni] = *(const bf16x8*)&Vs[ni * 16 + lo][ks2 * 32 + hi * 8];
#pragma unroll
            for (int mi = 0; mi < 2; ++mi)
#pragma unroll
                for (int ni = 0; ni < 4; ++ni)
                    o[mi][ni] = __builtin_amdgcn_mfma_f32_16x16x32_bf16(
                        pf[mi], vf[ni], o[mi][ni], 0, 0, 0);
        }
    }

    // ---- epilogue: ctx[b, s, h*64+dh] = O / l
#pragma unroll
    for (int mi = 0; mi < 2; ++mi)
#pragma unroll
        for (int r = 0; r < 4; ++r) {
            const int gq = q0 + w * 32 + mi * 16 + hi * 4 + r;
            const float rinv = 1.0f / lrow[mi][r];
#pragma unroll
            for (int ni = 0; ni < 4; ++ni) {
                const int dh = ni * 16 + lo;
                ctx[((size_t)(b * SEQ + gq)) * D_MODEL + h * DHEAD + dh] =
                    f2bf(o[mi][ni][r] * rinv);
            }
        }
}

// ---------------------------------------------------------------- launch
extern "C" void kernel_launch(void* const* d_in, const int* in_sizes, int n_in,
                              void* d_out, int out_size, void* d_ws, size_t ws_size,
                              hipStream_t stream) {
    const float* x  = (const float*)d_in[0];
    const float* Wq = (const float*)d_in[1];
    const float* bq = (const float*)d_in[2];
    const float* Wk = (const float*)d_in[3];
    const float* bk = (const float*)d_in[4];
    const float* Wv = (const float*)d_in[5];
    const float* bv = (const float*)d_in[6];
    const float* Wo = (const float*)d_in[7];
    const float* bo = (const float*)d_in[8];
    // d_in[9] = mask: known causal tril, implemented analytically.

    char* ws = (char*)d_ws;
    ushort* xb  = (ushort*)(ws);                    // 16 MiB  [8192,1024] bf16
    ushort* wb  = (ushort*)(ws + (16u << 20));      //  8 MiB  4x[1024,1024] bf16
    ushort* Qb  = (ushort*)(ws + (24u << 20));      // 16 MiB  [B,H,S,64]
    ushort* Kb  = (ushort*)(ws + (40u << 20));      // 16 MiB  [B,H,S,64]
    ushort* Vtb = (ushort*)(ws + (56u << 20));      // 16 MiB  [B,H,64,S]
    ushort* ctx = (ushort*)(ws + (72u << 20));      // 16 MiB  [B,S,1024]

    convert_kernel<<<2048, 256, 0, stream>>>(
        (const float4*)x, (const float4*)Wq, (const float4*)Wk,
        (const float4*)Wv, (const float4*)Wo, (ushort4*)xb, (ushort4*)wb);

    const int NW = D_MODEL * D_MODEL;
    dim3 ggrid(D_MODEL / 128, MTOT / 128);   // (8, 64)
    gemm_bt<0><<<ggrid, 256, 0, stream>>>(xb, wb + 0 * NW, bq, Qb, 0.125f);
    gemm_bt<0><<<ggrid, 256, 0, stream>>>(xb, wb + 1 * NW, bk, Kb, 1.0f);
    gemm_bt<1><<<ggrid, 256, 0, stream>>>(xb, wb + 2 * NW, bv, Vtb, 1.0f);

    dim3 agrid(SEQ / 128, NHEAD, BATCH);     // (16, 16, 4)
    attn_kernel<<<agrid, 256, 0, stream>>>(Qb, Kb, Vtb, ctx);

    gemm_bt<2><<<ggrid, 256, 0, stream>>>(ctx, wb + 3 * NW, bo, (float*)d_out, 1.0f);
}

// Round 2
// 235.248 us; speedup vs baseline: 1.4908x; 1.4908x over previous
//
#include <hip/hip_runtime.h>
#include <stdint.h>

#define D_MODEL 1024
#define NHEAD   16
#define DHEAD   64
#define BATCH   4
#define SEQ     2048
#define MTOT    (BATCH*SEQ)   // 8192

typedef __attribute__((ext_vector_type(4))) float f32x4;
typedef __attribute__((ext_vector_type(8))) short bf16x8;

typedef __attribute__((address_space(3))) uint32_t lds_u32;
typedef const __attribute__((address_space(1))) uint32_t glb_u32;

__device__ static inline void gload_lds16(const void* g, void* l) {
    __builtin_amdgcn_global_load_lds((glb_u32*)g, (lds_u32*)l, 16, 0, 0);
}

__device__ static inline ushort f2bf(float f) {
    uint32_t u = __builtin_bit_cast(uint32_t, f);
    u += 0x7fffu + ((u >> 16) & 1u);   // RNE (inputs are finite)
    return (ushort)(u >> 16);
}

// ---------------------------------------------------------------- convert
__global__ __launch_bounds__(256) void convert_kernel(
    const float4* __restrict__ x,
    const float4* __restrict__ wq, const float4* __restrict__ wk,
    const float4* __restrict__ wv, const float4* __restrict__ wo,
    ushort4* __restrict__ xb, ushort4* __restrict__ wb)
{
    const int NX4 = (MTOT * D_MODEL) / 4;
    const int NW4 = (D_MODEL * D_MODEL) / 4;
    const int TOT = NX4 + 4 * NW4;
    for (int i = blockIdx.x * blockDim.x + threadIdx.x; i < TOT;
         i += gridDim.x * blockDim.x) {
        float4 v; ushort4* dst;
        if (i < NX4) { v = x[i]; dst = &xb[i]; }
        else {
            int j = i - NX4;
            int w = j >> 18;
            int r = j & (NW4 - 1);
            const float4* s = (w == 0) ? wq : (w == 1) ? wk : (w == 2) ? wv : wo;
            v = s[r]; dst = &wb[(size_t)w * NW4 + r];
        }
        ushort4 o;
        o.x = f2bf(v.x); o.y = f2bf(v.y); o.z = f2bf(v.z); o.w = f2bf(v.w);
        *dst = o;
    }
}

// ---------------------------------------------------------------- GEMM
// C[i,e] = (sum_k A[i,k]*W[e,k] + bias[e]) * scale
template<int LAYOUT>
__global__ __launch_bounds__(256) void gemm_bt(
    const ushort* __restrict__ A,
    const ushort* __restrict__ W,
    const float*  __restrict__ bias,
    void* __restrict__ out, float scale)
{
    __shared__ __align__(16) ushort As[128 * 32];
    __shared__ __align__(16) ushort Bs[128 * 32];

    const int tid = threadIdx.x;
    const int w  = tid >> 6, l = tid & 63, lo = l & 15, hi = l >> 4;
    const int wr = w >> 1, wc = w & 1;

    // XCD-aware remap: XCD (id&7) owns contiguous m-chunk (8 m-blocks = 2MB A)
    // and streams all 8 n-blocks (W 2MB) -> both L2-resident per XCD.
    const int id = blockIdx.y * 8 + blockIdx.x;        // 0..511, dispatch order
    const int mb = ((id & 7) << 3) | ((id >> 3) & 7);  // 0..63
    const int nb = id >> 6;                            // 0..7
    const int m0 = mb * 128, n0 = nb * 128;

    f32x4 acc[4][4] = {};

    const int srow = l >> 2;
    const int sk   = (l & 3) * 8;

    for (int kt = 0; kt < 32; ++kt) {
        const int k0 = kt * 32;
        __syncthreads();
#pragma unroll
        for (int c = 0; c < 2; ++c) {
            const int row = c * 64 + w * 16 + srow;
            gload_lds16(&A[(size_t)(m0 + row) * 1024 + k0 + sk],
                        &As[(c * 64 + w * 16) * 32]);
            gload_lds16(&W[(size_t)(n0 + row) * 1024 + k0 + sk],
                        &Bs[(c * 64 + w * 16) * 32]);
        }
        __syncthreads();

        bf16x8 af[4], bfr[4];
#pragma unroll
        for (int mi = 0; mi < 4; ++mi)
            af[mi] = *(const bf16x8*)&As[(wr * 64 + mi * 16 + lo) * 32 + hi * 8];
#pragma unroll
        for (int ni = 0; ni < 4; ++ni)
            bfr[ni] = *(const bf16x8*)&Bs[(wc * 64 + ni * 16 + lo) * 32 + hi * 8];
#pragma unroll
        for (int mi = 0; mi < 4; ++mi)
#pragma unroll
            for (int ni = 0; ni < 4; ++ni)
                acc[mi][ni] = __builtin_amdgcn_mfma_f32_16x16x32_bf16(
                    af[mi], bfr[ni], acc[mi][ni], 0, 0, 0);
    }

#pragma unroll
    for (int mi = 0; mi < 4; ++mi) {
#pragma unroll
        for (int ni = 0; ni < 4; ++ni) {
            const int gj = n0 + wc * 64 + ni * 16 + lo;
            const float bj = bias[gj];
            if (LAYOUT == 0) {
#pragma unroll
                for (int r = 0; r < 4; ++r) {
                    const int gi = m0 + wr * 64 + mi * 16 + hi * 4 + r;
                    const int b = gi >> 11, s = gi & (SEQ - 1);
                    const int h = gj >> 6, dh = gj & 63;
                    ((ushort*)out)[(((size_t)(b * NHEAD + h)) * SEQ + s) * DHEAD + dh] =
                        f2bf((acc[mi][ni][r] + bj) * scale);
                }
            } else if (LAYOUT == 1) {
                const int gi0 = m0 + wr * 64 + mi * 16 + hi * 4;
                const int b = gi0 >> 11, s = gi0 & (SEQ - 1);
                const int h = gj >> 6, dh = gj & 63;
                ushort4 o4;
                o4.x = f2bf((acc[mi][ni][0] + bj) * scale);
                o4.y = f2bf((acc[mi][ni][1] + bj) * scale);
                o4.z = f2bf((acc[mi][ni][2] + bj) * scale);
                o4.w = f2bf((acc[mi][ni][3] + bj) * scale);
                *(ushort4*)&((ushort*)out)[(((size_t)(b * NHEAD + h)) * DHEAD + dh) * SEQ + s] = o4;
            } else {
#pragma unroll
                for (int r = 0; r < 4; ++r) {
                    const int gi = m0 + wr * 64 + mi * 16 + hi * 4 + r;
                    ((float*)out)[(size_t)gi * D_MODEL + gj] = (acc[mi][ni][r] + bj) * scale;
                }
            }
        }
    }
}

// ---------------------------------------------------------------- attention
// Swapped-QK^T flash attention. Q pre-scaled by 1/8.
// Q [B,H,S,64], K [B,H,S,64], Vt [B,H,64,S] -> ctx [B,S,1024] (bf16)
// LDS tiles [64][64] bf16 with 16B-granule XOR swizzle: byte(row,col) =
//   row*128 + (((col>>3) ^ (row&7))<<4) + (col&7)*2
__global__ __launch_bounds__(256) void attn_kernel(
    const ushort* __restrict__ Q, const ushort* __restrict__ K,
    const ushort* __restrict__ Vt, ushort* __restrict__ ctx)
{
    __shared__ __align__(16) ushort Ks[64 * 64];
    __shared__ __align__(16) ushort Vs[64 * 64];
    __shared__ __align__(16) ushort Pq[4 * 32 * 64];   // per-wave P [q32][kv64]

    const int tid = threadIdx.x;
    const int w = tid >> 6, l = tid & 63, lo = l & 15, hi = l >> 4;
    const int sw = lo & 7;

    // XCD/balance swizzle: same (b,h) -> same XCD; co-resident qt mixed.
    const int fid = blockIdx.x;                 // 0..1023
    const int xcd = fid & 7, t0 = fid >> 3;     // t0 0..127
    const int gHi = t0 >> 4, j = t0 & 15;
    const int g = xcd + 8 * gHi;                // (b,h) group, g%8==xcd
    const int b = g >> 4, h = g & 15;
    const int qt = (j + 2 * gHi) & 15;
    const int q0 = qt * 128;
    const int qw0 = q0 + w * 32;
    const size_t base = (size_t)(b * NHEAD + h) * SEQ * DHEAD;

    // Q fragments (B-operand): col=q=lo, k=dh=ks*32+hi*8+j
    bf16x8 qf[2][2];
#pragma unroll
    for (int mi = 0; mi < 2; ++mi)
#pragma unroll
        for (int ks = 0; ks < 2; ++ks)
            qf[mi][ks] = *(const bf16x8*)&Q[base +
                (size_t)(qw0 + mi * 16 + lo) * DHEAD + ks * 32 + hi * 8];

    f32x4 o[2][4] = {};
    float mrow[2] = {-1e30f, -1e30f}, lrow[2] = {0.f, 0.f};

    const int ntiles = (q0 + 128) >> 6;
    const int krow = tid >> 3;           // 0..31
    const int kcol = (tid & 7) * 8;

    bf16x8 kreg[2], vreg[2];
#pragma unroll
    for (int c = 0; c < 2; ++c) {
        kreg[c] = *(const bf16x8*)&K[base + (size_t)(c * 32 + krow) * DHEAD + kcol];
        vreg[c] = *(const bf16x8*)&Vt[base + (size_t)(c * 32 + krow) * SEQ + kcol];
    }

    char* PqW = (char*)&Pq[w * 2048];

    for (int t = 0; t < ntiles; ++t) {
        const int kv0 = t << 6;
        __syncthreads();                     // prev tile's LDS reads done
#pragma unroll
        for (int c = 0; c < 2; ++c) {        // stage K/V (swizzled)
            const int row = c * 32 + krow;
            const int g16 = (tid & 7) ^ (row & 7);
            *(bf16x8*)((char*)Ks + row * 128 + (g16 << 4)) = kreg[c];
            *(bf16x8*)((char*)Vs + row * 128 + (g16 << 4)) = vreg[c];
        }
        __syncthreads();
        if (t + 1 < ntiles) {                // prefetch next tile (T14)
            const int nv0 = kv0 + 64;
#pragma unroll
            for (int c = 0; c < 2; ++c) {
                kreg[c] = *(const bf16x8*)&K[base + (size_t)(nv0 + c * 32 + krow) * DHEAD + kcol];
                vreg[c] = *(const bf16x8*)&Vt[base + (size_t)(c * 32 + krow) * SEQ + nv0 + kcol];
            }
        }
        if (kv0 > qw0 + 31) continue;        // wave fully masked (uniform; barriers balanced)

        // ---- S^T = K Q^T : s[mi][nj] rows=kv(hi*4+r in nj), cols=q(lo in mi)
        f32x4 s[2][4] = {};
#pragma unroll
        for (int ks = 0; ks < 2; ++ks) {
            bf16x8 kf[4];
#pragma unroll
            for (int nj = 0; nj < 4; ++nj)
                kf[nj] = *(const bf16x8*)((char*)Ks + (nj * 16 + lo) * 128 +
                                          ((((ks << 2) + hi) ^ sw) << 4));
#pragma unroll
            for (int mi = 0; mi < 2; ++mi)
#pragma unroll
                for (int nj = 0; nj < 4; ++nj)
                    s[mi][nj] = __builtin_amdgcn_mfma_f32_16x16x32_bf16(
                        kf[nj], qf[mi][ks], s[mi][nj], 0, 0, 0);
        }

        // ---- causal mask
        if (kv0 + 63 > qw0) {
#pragma unroll
            for (int mi = 0; mi < 2; ++mi) {
                const int gq = qw0 + mi * 16 + lo;
#pragma unroll
                for (int nj = 0; nj < 4; ++nj)
#pragma unroll
                    for (int r = 0; r < 4; ++r) {
                        const int gk = kv0 + nj * 16 + hi * 4 + r;
                        if (gk > gq) s[mi][nj][r] = -1e30f;
                    }
            }
        }

        // ---- online softmax (row q=lo lane-local; reduce over hi groups)
        float tl[2], corr[2];
#pragma unroll
        for (int mi = 0; mi < 2; ++mi) {
            float m = s[mi][0][0];
#pragma unroll
            for (int nj = 0; nj < 4; ++nj)
#pragma unroll
                for (int r = 0; r < 4; ++r) m = fmaxf(m, s[mi][nj][r]);
            tl[mi] = m;
        }
        const bool grow = (tl[0] > mrow[0]) | (tl[1] > mrow[1]);
        if (__any(grow)) {                   // full path
#pragma unroll
            for (int mi = 0; mi < 2; ++mi) {
                float m2 = fmaxf(tl[mi], __shfl_xor(tl[mi], 16));
                m2 = fmaxf(m2, __shfl_xor(m2, 32));
                const float mn = fmaxf(mrow[mi], m2);
                corr[mi] = __expf(mrow[mi] - mn);
                mrow[mi] = mn;
            }
#pragma unroll
            for (int mi = 0; mi < 2; ++mi)
#pragma unroll
                for (int r = 0; r < 4; ++r) {
                    const float cb = __shfl(corr[mi], hi * 4 + r);
#pragma unroll
                    for (int ni = 0; ni < 4; ++ni) o[mi][ni][r] *= cb;
                }
        } else { corr[0] = 1.f; corr[1] = 1.f; }   // defer-max skip (T13)

#pragma unroll
        for (int mi = 0; mi < 2; ++mi) {
            float ls = 0.f;
#pragma unroll
            for (int nj = 0; nj < 4; ++nj) {
#pragma unroll
                for (int r = 0; r < 4; ++r) {
                    const float p = __expf(s[mi][nj][r] - mrow[mi]);
                    s[mi][nj][r] = p;
                    ls += p;
                }
                // vectorized P write: q=mi*16+lo, kv=nj*16+hi*4+r
                ushort4 p4;
                p4.x = f2bf(s[mi][nj][0]); p4.y = f2bf(s[mi][nj][1]);
                p4.z = f2bf(s[mi][nj][2]); p4.w = f2bf(s[mi][nj][3]);
                const int gP = ((nj << 1) + (hi >> 1)) ^ sw;
                *(ushort4*)(PqW + (mi * 16 + lo) * 128 + (gP << 4) + ((hi & 1) << 3)) = p4;
            }
            ls += __shfl_xor(ls, 16);
            ls += __shfl_xor(ls, 32);
            lrow[mi] = lrow[mi] * corr[mi] + ls;
        }

        // ---- O += P V  (A=P row-major from Pq, B=V from Vs[dh][kv])
#pragma unroll
        for (int ks2 = 0; ks2 < 2; ++ks2) {
            bf16x8 pf[2], vf[4];
#pragma unroll
            for (int mi = 0; mi < 2; ++mi)
                pf[mi] = *(const bf16x8*)(PqW + (mi * 16 + lo) * 128 +
                                          ((((ks2 << 2) + hi) ^ sw) << 4));
#pragma unroll
            for (int ni = 0; ni < 4; ++ni)
                vf[ni] = *(const bf16x8*)((char*)Vs + (ni * 16 + lo) * 128 +
                                          ((((ks2 << 2) + hi) ^ sw) << 4));
#pragma unroll
            for (int mi = 0; mi < 2; ++mi)
#pragma unroll
                for (int ni = 0; ni < 4; ++ni)
                    o[mi][ni] = __builtin_amdgcn_mfma_f32_16x16x32_bf16(
                        pf[mi], vf[ni], o[mi][ni], 0, 0, 0);
        }
    }

    // ---- epilogue
#pragma unroll
    for (int mi = 0; mi < 2; ++mi) {
        const float rv = 1.0f / lrow[mi];
#pragma unroll
        for (int r = 0; r < 4; ++r) {
            const float rb = __shfl(rv, hi * 4 + r);
            const int gq = qw0 + mi * 16 + hi * 4 + r;
#pragma unroll
            for (int ni = 0; ni < 4; ++ni)
                ctx[((size_t)(b * SEQ + gq)) * D_MODEL + h * DHEAD + ni * 16 + lo] =
                    f2bf(o[mi][ni][r] * rb);
        }
    }
}

// ---------------------------------------------------------------- launch
extern "C" void kernel_launch(void* const* d_in, const int* in_sizes, int n_in,
                              void* d_out, int out_size, void* d_ws, size_t ws_size,
                              hipStream_t stream) {
    const float* x  = (const float*)d_in[0];
    const float* Wq = (const float*)d_in[1];
    const float* bq = (const float*)d_in[2];
    const float* Wk = (const float*)d_in[3];
    const float* bk = (const float*)d_in[4];
    const float* Wv = (const float*)d_in[5];
    const float* bv = (const float*)d_in[6];
    const float* Wo = (const float*)d_in[7];
    const float* bo = (const float*)d_in[8];

    char* ws = (char*)d_ws;
    ushort* xb  = (ushort*)(ws);
    ushort* wb  = (ushort*)(ws + (16u << 20));
    ushort* Qb  = (ushort*)(ws + (24u << 20));
    ushort* Kb  = (ushort*)(ws + (40u << 20));
    ushort* Vtb = (ushort*)(ws + (56u << 20));
    ushort* ctx = (ushort*)(ws + (72u << 20));

    convert_kernel<<<2048, 256, 0, stream>>>(
        (const float4*)x, (const float4*)Wq, (const float4*)Wk,
        (const float4*)Wv, (const float4*)Wo, (ushort4*)xb, (ushort4*)wb);

    const int NW = D_MODEL * D_MODEL;
    dim3 ggrid(D_MODEL / 128, MTOT / 128);
    gemm_bt<0><<<ggrid, 256, 0, stream>>>(xb, wb + 0 * NW, bq, Qb, 0.125f);
    gemm_bt<0><<<ggrid, 256, 0, stream>>>(xb, wb + 1 * NW, bk, Kb, 1.0f);
    gemm_bt<1><<<ggrid, 256, 0, stream>>>(xb, wb + 2 * NW, bv, Vtb, 1.0f);

    attn_kernel<<<1024, 256, 0, stream>>>(Qb, Kb, Vtb, ctx);

    gemm_bt<2><<<ggrid, 256, 0, stream>>>(ctx, wb + 3 * NW, bo, (float*)d_out, 1.0f);
}

// Round 3
// 184.512 us; speedup vs baseline: 1.9007x; 1.2750x over previous
//
#include <hip/hip_runtime.h>
#include <stdint.h>

#define D_MODEL 1024
#define NHEAD   16
#define DHEAD   64
#define BATCH   4
#define SEQ     2048
#define MTOT    (BATCH*SEQ)   // 8192

typedef __attribute__((ext_vector_type(4))) float f32x4;
typedef __attribute__((ext_vector_type(8))) short bf16x8;

typedef __attribute__((address_space(3))) uint32_t lds_u32;
typedef const __attribute__((address_space(1))) uint32_t glb_u32;

__device__ static inline void gload_lds16(const void* g, void* l) {
    __builtin_amdgcn_global_load_lds((glb_u32*)g, (lds_u32*)l, 16, 0, 0);
}

__device__ static inline ushort f2bf(float f) {
    uint32_t u = __builtin_bit_cast(uint32_t, f);
    u += 0x7fffu + ((u >> 16) & 1u);   // RNE (inputs are finite)
    return (ushort)(u >> 16);
}

__device__ static inline float exp2_fast(float x) {
    float r; asm("v_exp_f32 %0, %1" : "=v"(r) : "v"(x)); return r;
}
__device__ static inline uint32_t cvt_pk_bf16(float a, float b) {
    uint32_t r;  // low half = bf16(a), high half = bf16(b)
    asm("v_cvt_pk_bf16_f32 %0, %1, %2" : "=v"(r) : "v"(a), "v"(b));
    return r;
}

// ---------------------------------------------------------------- convert
__global__ __launch_bounds__(256) void convert_kernel(
    const float4* __restrict__ x,
    const float4* __restrict__ wq, const float4* __restrict__ wk,
    const float4* __restrict__ wv, const float4* __restrict__ wo,
    ushort4* __restrict__ xb, ushort4* __restrict__ wb)
{
    const int NX4 = (MTOT * D_MODEL) / 4;
    const int NW4 = (D_MODEL * D_MODEL) / 4;
    const int TOT = NX4 + 4 * NW4;
    for (int i = blockIdx.x * blockDim.x + threadIdx.x; i < TOT;
         i += gridDim.x * blockDim.x) {
        float4 v; ushort4* dst;
        if (i < NX4) { v = x[i]; dst = &xb[i]; }
        else {
            int j = i - NX4;
            int w = j >> 18;
            int r = j & (NW4 - 1);
            const float4* s = (w == 0) ? wq : (w == 1) ? wk : (w == 2) ? wv : wo;
            v = s[r]; dst = &wb[(size_t)w * NW4 + r];
        }
        ushort4 o;
        o.x = f2bf(v.x); o.y = f2bf(v.y); o.z = f2bf(v.z); o.w = f2bf(v.w);
        *dst = o;
    }
}

// ---------------------------------------------------------------- GEMM
// C[i,e] = (sum_k A[i,k]*W[e,k] + bias[e]) * scale
template<int LAYOUT>
__global__ __launch_bounds__(256) void gemm_bt(
    const ushort* __restrict__ A,
    const ushort* __restrict__ W,
    const float*  __restrict__ bias,
    void* __restrict__ out, float scale)
{
    __shared__ __align__(16) ushort As[128 * 32];
    __shared__ __align__(16) ushort Bs[128 * 32];

    const int tid = threadIdx.x;
    const int w  = tid >> 6, l = tid & 63, lo = l & 15, hi = l >> 4;
    const int wr = w >> 1, wc = w & 1;

    const int id = blockIdx.y * 8 + blockIdx.x;        // 0..511
    const int mb = ((id & 7) << 3) | ((id >> 3) & 7);  // 0..63
    const int nb = id >> 6;                            // 0..7
    const int m0 = mb * 128, n0 = nb * 128;

    f32x4 acc[4][4] = {};

    const int srow = l >> 2;
    const int sk   = (l & 3) * 8;

    for (int kt = 0; kt < 32; ++kt) {
        const int k0 = kt * 32;
        __syncthreads();
#pragma unroll
        for (int c = 0; c < 2; ++c) {
            const int row = c * 64 + w * 16 + srow;
            gload_lds16(&A[(size_t)(m0 + row) * 1024 + k0 + sk],
                        &As[(c * 64 + w * 16) * 32]);
            gload_lds16(&W[(size_t)(n0 + row) * 1024 + k0 + sk],
                        &Bs[(c * 64 + w * 16) * 32]);
        }
        __syncthreads();

        bf16x8 af[4], bfr[4];
#pragma unroll
        for (int mi = 0; mi < 4; ++mi)
            af[mi] = *(const bf16x8*)&As[(wr * 64 + mi * 16 + lo) * 32 + hi * 8];
#pragma unroll
        for (int ni = 0; ni < 4; ++ni)
            bfr[ni] = *(const bf16x8*)&Bs[(wc * 64 + ni * 16 + lo) * 32 + hi * 8];
#pragma unroll
        for (int mi = 0; mi < 4; ++mi)
#pragma unroll
            for (int ni = 0; ni < 4; ++ni)
                acc[mi][ni] = __builtin_amdgcn_mfma_f32_16x16x32_bf16(
                    af[mi], bfr[ni], acc[mi][ni], 0, 0, 0);
    }

#pragma unroll
    for (int mi = 0; mi < 4; ++mi) {
#pragma unroll
        for (int ni = 0; ni < 4; ++ni) {
            const int gj = n0 + wc * 64 + ni * 16 + lo;
            const float bj = bias[gj];
            if (LAYOUT == 0) {
#pragma unroll
                for (int r = 0; r < 4; ++r) {
                    const int gi = m0 + wr * 64 + mi * 16 + hi * 4 + r;
                    const int b = gi >> 11, s = gi & (SEQ - 1);
                    const int h = gj >> 6, dh = gj & 63;
                    ((ushort*)out)[(((size_t)(b * NHEAD + h)) * SEQ + s) * DHEAD + dh] =
                        f2bf((acc[mi][ni][r] + bj) * scale);
                }
            } else if (LAYOUT == 1) {
                const int gi0 = m0 + wr * 64 + mi * 16 + hi * 4;
                const int b = gi0 >> 11, s = gi0 & (SEQ - 1);
                const int h = gj >> 6, dh = gj & 63;
                ushort4 o4;
                o4.x = f2bf((acc[mi][ni][0] + bj) * scale);
                o4.y = f2bf((acc[mi][ni][1] + bj) * scale);
                o4.z = f2bf((acc[mi][ni][2] + bj) * scale);
                o4.w = f2bf((acc[mi][ni][3] + bj) * scale);
                *(ushort4*)&((ushort*)out)[(((size_t)(b * NHEAD + h)) * DHEAD + dh) * SEQ + s] = o4;
            } else {
#pragma unroll
                for (int r = 0; r < 4; ++r) {
                    const int gi = m0 + wr * 64 + mi * 16 + hi * 4 + r;
                    ((float*)out)[(size_t)gi * D_MODEL + gj] = (acc[mi][ni][r] + bj) * scale;
                }
            }
        }
    }
}

// ---------------------------------------------------------------- attention
// Swapped-QK^T flash attention, exp2 domain (Q pre-scaled by log2e/8).
// Each block: one (b,h), Q-tile pair {j, 15-j}  -> uniform 34 KV-tiles/block.
// LDS [64][64] bf16, 16B-granule XOR swizzle.
__global__ __launch_bounds__(256) void attn_kernel(
    const ushort* __restrict__ Q, const ushort* __restrict__ K,
    const ushort* __restrict__ Vt, ushort* __restrict__ ctx)
{
    __shared__ __align__(16) ushort Ks[64 * 64];
    __shared__ __align__(16) ushort Vs[64 * 64];
    __shared__ __align__(16) ushort Pq[4 * 32 * 64];

    const int tid = threadIdx.x;
    const int w = tid >> 6, l = tid & 63, lo = l & 15, hi = l >> 4;
    const int sw = lo & 7;

    const int fid = blockIdx.x;            // 0..511
    const int xcd = fid & 7;
    const int u = fid >> 3;                // 0..63
    const int g = xcd * 8 + (u & 7);       // bh; g>>3 == xcd
    const int b = g >> 4, h = g & 15;
    const int j = u >> 3;                  // 0..7
    const size_t base = (size_t)(b * NHEAD + h) * SEQ * DHEAD;

    const int krow = tid >> 3;             // 0..31
    const int kcol = (tid & 7) * 8;
    char* PqW = (char*)&Pq[w * 2048];

    for (int pass = 0; pass < 2; ++pass) {
        const int qt = pass ? (15 - j) : j;
        const int q0 = qt << 7;
        const int qw0 = q0 + w * 32;

        bf16x8 qf[2][2];
#pragma unroll
        for (int mi = 0; mi < 2; ++mi)
#pragma unroll
            for (int ks = 0; ks < 2; ++ks)
                qf[mi][ks] = *(const bf16x8*)&Q[base +
                    (size_t)(qw0 + mi * 16 + lo) * DHEAD + ks * 32 + hi * 8];

        f32x4 o[2][4] = {};
        float mrow[2] = {-1e30f, -1e30f}, lrow[2] = {0.f, 0.f};

        const int ntiles = (q0 + 128) >> 6;
        bf16x8 kreg[2], vreg[2];
#pragma unroll
        for (int c = 0; c < 2; ++c) {
            kreg[c] = *(const bf16x8*)&K[base + (size_t)(c * 32 + krow) * DHEAD + kcol];
            vreg[c] = *(const bf16x8*)&Vt[base + (size_t)(c * 32 + krow) * SEQ + kcol];
        }

        for (int t = 0; t < ntiles; ++t) {
            const int kv0 = t << 6;
            __syncthreads();                 // prev tile's LDS reads done
#pragma unroll
            for (int c = 0; c < 2; ++c) {    // stage K/V (swizzled)
                const int row = c * 32 + krow;
                const int g16 = (tid & 7) ^ (row & 7);
                *(bf16x8*)((char*)Ks + row * 128 + (g16 << 4)) = kreg[c];
                *(bf16x8*)((char*)Vs + row * 128 + (g16 << 4)) = vreg[c];
            }
            __syncthreads();
            if (t + 1 < ntiles) {            // prefetch next tile (T14)
                const int nv0 = kv0 + 64;
#pragma unroll
                for (int c = 0; c < 2; ++c) {
                    kreg[c] = *(const bf16x8*)&K[base + (size_t)(nv0 + c * 32 + krow) * DHEAD + kcol];
                    vreg[c] = *(const bf16x8*)&Vt[base + (size_t)(c * 32 + krow) * SEQ + nv0 + kcol];
                }
            }
            if (kv0 > qw0 + 31) continue;    // wave fully masked

            // ---- S^T = K Q^T  (rows=kv, cols=q=lo), log2-scaled
            f32x4 s[2][4] = {};
#pragma unroll
            for (int ks = 0; ks < 2; ++ks) {
                bf16x8 kf[4];
#pragma unroll
                for (int nj = 0; nj < 4; ++nj)
                    kf[nj] = *(const bf16x8*)((char*)Ks + (nj * 16 + lo) * 128 +
                                              ((((ks << 2) + hi) ^ sw) << 4));
#pragma unroll
                for (int mi = 0; mi < 2; ++mi)
#pragma unroll
                    for (int nj = 0; nj < 4; ++nj)
                        s[mi][nj] = __builtin_amdgcn_mfma_f32_16x16x32_bf16(
                            kf[nj], qf[mi][ks], s[mi][nj], 0, 0, 0);
            }

            // ---- causal mask
            if (kv0 + 63 > qw0) {
#pragma unroll
                for (int mi = 0; mi < 2; ++mi) {
                    const int gq = qw0 + mi * 16 + lo;
#pragma unroll
                    for (int nj = 0; nj < 4; ++nj)
#pragma unroll
                        for (int r = 0; r < 4; ++r) {
                            const int gk = kv0 + nj * 16 + hi * 4 + r;
                            if (gk > gq) s[mi][nj][r] = -1e30f;
                        }
                }
            }

            // ---- online softmax (q=lo lane-local), defer-max THR=8 (log2)
            float tl[2], corr[2];
#pragma unroll
            for (int mi = 0; mi < 2; ++mi) {
                float m = s[mi][0][0];
#pragma unroll
                for (int nj = 0; nj < 4; ++nj)
#pragma unroll
                    for (int r = 0; r < 4; ++r) m = fmaxf(m, s[mi][nj][r]);
                tl[mi] = m;
            }
            const bool grow = (tl[0] > mrow[0] + 8.f) | (tl[1] > mrow[1] + 8.f);
            if (__any(grow)) {
#pragma unroll
                for (int mi = 0; mi < 2; ++mi) {
                    float m2 = fmaxf(tl[mi], __shfl_xor(tl[mi], 16));
                    m2 = fmaxf(m2, __shfl_xor(m2, 32));
                    const float mn = fmaxf(mrow[mi], m2);
                    corr[mi] = exp2_fast(mrow[mi] - mn);
                    mrow[mi] = mn;
                }
#pragma unroll
                for (int mi = 0; mi < 2; ++mi)
#pragma unroll
                    for (int r = 0; r < 4; ++r) {
                        const float cb = __shfl(corr[mi], hi * 4 + r);
#pragma unroll
                        for (int ni = 0; ni < 4; ++ni) o[mi][ni][r] *= cb;
                    }
            } else { corr[0] = 1.f; corr[1] = 1.f; }

#pragma unroll
            for (int mi = 0; mi < 2; ++mi) {
                float ls = 0.f;
#pragma unroll
                for (int nj = 0; nj < 4; ++nj) {
#pragma unroll
                    for (int r = 0; r < 4; ++r) {
                        const float p = exp2_fast(s[mi][nj][r] - mrow[mi]);
                        s[mi][nj][r] = p;
                        ls += p;
                    }
                    uint2 pp;
                    pp.x = cvt_pk_bf16(s[mi][nj][0], s[mi][nj][1]);
                    pp.y = cvt_pk_bf16(s[mi][nj][2], s[mi][nj][3]);
                    const int gP = ((nj << 1) + (hi >> 1)) ^ sw;
                    *(uint2*)(PqW + (mi * 16 + lo) * 128 + (gP << 4) + ((hi & 1) << 3)) = pp;
                }
                ls += __shfl_xor(ls, 16);
                ls += __shfl_xor(ls, 32);
                lrow[mi] = lrow[mi] * corr[mi] + ls;
            }

            // ---- O += P V
#pragma unroll
            for (int ks2 = 0; ks2 < 2; ++ks2) {
                bf16x8 pf[2], vf[4];
#pragma unroll
                for (int mi = 0; mi < 2; ++mi)
                    pf[mi] = *(const bf16x8*)(PqW + (mi * 16 + lo) * 128 +
                                              ((((ks2 << 2) + hi) ^ sw) << 4));
#pragma unroll
                for (int ni = 0; ni < 4; ++ni)
                    vf[ni] = *(const bf16x8*)((char*)Vs + (ni * 16 + lo) * 128 +
                                              ((((ks2 << 2) + hi) ^ sw) << 4));
#pragma unroll
                for (int mi = 0; mi < 2; ++mi)
#pragma unroll
                    for (int ni = 0; ni < 4; ++ni)
                        o[mi][ni] = __builtin_amdgcn_mfma_f32_16x16x32_bf16(
                            pf[mi], vf[ni], o[mi][ni], 0, 0, 0);
            }
        }

        // ---- epilogue for this Q-tile
#pragma unroll
        for (int mi = 0; mi < 2; ++mi) {
            const float rv = 1.0f / lrow[mi];
#pragma unroll
            for (int r = 0; r < 4; ++r) {
                const float rb = __shfl(rv, hi * 4 + r);
                const int gq = qw0 + mi * 16 + hi * 4 + r;
#pragma unroll
                for (int ni = 0; ni < 4; ++ni)
                    ctx[((size_t)(b * SEQ + gq)) * D_MODEL + h * DHEAD + ni * 16 + lo] =
                        f2bf(o[mi][ni][r] * rb);
            }
        }
    }
}

// ---------------------------------------------------------------- launch
extern "C" void kernel_launch(void* const* d_in, const int* in_sizes, int n_in,
                              void* d_out, int out_size, void* d_ws, size_t ws_size,
                              hipStream_t stream) {
    const float* x  = (const float*)d_in[0];
    const float* Wq = (const float*)d_in[1];
    const float* bq = (const float*)d_in[2];
    const float* Wk = (const float*)d_in[3];
    const float* bk = (const float*)d_in[4];
    const float* Wv = (const float*)d_in[5];
    const float* bv = (const float*)d_in[6];
    const float* Wo = (const float*)d_in[7];
    const float* bo = (const float*)d_in[8];

    char* ws = (char*)d_ws;
    ushort* xb  = (ushort*)(ws);
    ushort* wb  = (ushort*)(ws + (16u << 20));
    ushort* Qb  = (ushort*)(ws + (24u << 20));
    ushort* Kb  = (ushort*)(ws + (40u << 20));
    ushort* Vtb = (ushort*)(ws + (56u << 20));
    ushort* ctx = (ushort*)(ws + (72u << 20));

    convert_kernel<<<2048, 256, 0, stream>>>(
        (const float4*)x, (const float4*)Wq, (const float4*)Wk,
        (const float4*)Wv, (const float4*)Wo, (ushort4*)xb, (ushort4*)wb);

    const int NW = D_MODEL * D_MODEL;
    dim3 ggrid(D_MODEL / 128, MTOT / 128);
    const float qscale = 0.125f * 1.44269504f;   // fold log2e: softmax in exp2 domain
    gemm_bt<0><<<ggrid, 256, 0, stream>>>(xb, wb + 0 * NW, bq, Qb, qscale);
    gemm_bt<0><<<ggrid, 256, 0, stream>>>(xb, wb + 1 * NW, bk, Kb, 1.0f);
    gemm_bt<1><<<ggrid, 256, 0, stream>>>(xb, wb + 2 * NW, bv, Vtb, 1.0f);

    attn_kernel<<<512, 256, 0, stream>>>(Qb, Kb, Vtb, ctx);

    gemm_bt<2><<<ggrid, 256, 0, stream>>>(ctx, wb + 3 * NW, bo, (float*)d_out, 1.0f);
}